// Round 1
// baseline (357.159 us; speedup 1.0000x reference)
//
#include <hip/hip_runtime.h>
#include <hip/hip_bf16.h>

typedef __attribute__((ext_vector_type(8))) short short8;
typedef __attribute__((ext_vector_type(4))) float floatx4;

static __device__ __forceinline__ short f2bf(float f) {
    union { float f; unsigned u; } v; v.f = f;
    unsigned r = v.u + 0x7fffu + ((v.u >> 16) & 1u);
    return (short)(r >> 16);
}

#define C_CTX 10
#define D_EMB 128
#define E_DIM 256
#define BB1   8      // b per block (kernel1)
#define BM1   80     // rows per block = BB1 * C_CTX
#define LP    40     // LDS pitch in bf16 elems (80B rows: 16B-aligned, conflict-light)

// ---------------- Kernel 1: proj GEMM + bias + relu + segment-sum -> h (bf16) --------
__global__ __launch_bounds__(256, 2)
void k1_gemm_h(const int* __restrict__ tgt, const int* __restrict__ ctx,
               const float* __restrict__ R, const float* __restrict__ Mw,
               const float* __restrict__ Mb, __hip_bfloat16* __restrict__ h_out)
{
    __shared__ __align__(16) short lA[BM1 * LP];    // 80x32 bf16 tile (padded)
    __shared__ __align__(16) short lB[E_DIM * LP];  // 256x32 bf16 tile (padded)
    __shared__ float hT[BB1 * E_DIM];               // per-block h accumulator
    __shared__ int ids[BM1];
    __shared__ int tids[BB1];
    __shared__ float mbs[E_DIM];

    const int t = threadIdx.x;
    const int wave = t >> 6, lane = t & 63;
    const int b0 = blockIdx.x * BB1;
    const int fr = lane & 15, kg = lane >> 4;

    if (t < BM1) ids[t] = ctx[b0 * C_CTX + t];
    if (t >= 96 && t < 96 + BB1) tids[t - 96] = tgt[b0 + (t - 96)];
    mbs[t] = Mb[t];
    for (int i = t; i < BB1 * E_DIM; i += 256) hT[i] = 0.f;

    floatx4 acc[5][4];
    #pragma unroll
    for (int mi = 0; mi < 5; ++mi)
        #pragma unroll
        for (int ni = 0; ni < 4; ++ni)
            acc[mi][ni] = (floatx4){0.f, 0.f, 0.f, 0.f};

    for (int k0 = 0; k0 < E_DIM; k0 += 32) {
        __syncthreads();  // ids ready (iter0) / prior MFMA LDS reads done (iter>0)

        // stage A: 80 rows x 32 cols, gathered from R; first 128 k = context, last 128 = target
        for (int s = t; s < BM1 * 8; s += 256) {
            int r = s >> 3, ch = s & 7;
            const float* src;
            if (k0 < D_EMB) src = R + (size_t)ids[r] * D_EMB + (k0 + ch * 4);
            else            src = R + (size_t)tids[r / C_CTX] * D_EMB + (k0 - D_EMB + ch * 4);
            float4 v = *(const float4*)src;
            short* dst = &lA[r * LP + ch * 4];
            dst[0] = f2bf(v.x); dst[1] = f2bf(v.y); dst[2] = f2bf(v.z); dst[3] = f2bf(v.w);
        }
        // stage B: M_w rows e=0..255, cols k0..k0+31
        for (int s = t; s < E_DIM * 8; s += 256) {
            int e = s >> 3, ch = s & 7;
            float4 v = *(const float4*)(Mw + (size_t)e * E_DIM + k0 + ch * 4);
            short* dst = &lB[e * LP + ch * 4];
            dst[0] = f2bf(v.x); dst[1] = f2bf(v.y); dst[2] = f2bf(v.z); dst[3] = f2bf(v.w);
        }
        __syncthreads();

        short8 bfr[4];
        #pragma unroll
        for (int ni = 0; ni < 4; ++ni)
            bfr[ni] = *(const short8*)&lB[(wave * 64 + ni * 16 + fr) * LP + kg * 8];
        #pragma unroll
        for (int mi = 0; mi < 5; ++mi) {
            short8 afr = *(const short8*)&lA[(mi * 16 + fr) * LP + kg * 8];
            #pragma unroll
            for (int ni = 0; ni < 4; ++ni)
                acc[mi][ni] = __builtin_amdgcn_mfma_f32_16x16x32_bf16(afr, bfr[ni], acc[mi][ni], 0, 0, 0);
        }
    }

    // epilogue: +bias, relu, segment-sum over C into hT
    #pragma unroll
    for (int mi = 0; mi < 5; ++mi)
        #pragma unroll
        for (int ni = 0; ni < 4; ++ni) {
            int col = wave * 64 + ni * 16 + fr;
            float bias = mbs[col];
            #pragma unroll
            for (int j = 0; j < 4; ++j) {
                int rl = mi * 16 + (lane >> 4) * 4 + j;   // 0..79
                float v = acc[mi][ni][j] + bias;
                v = fmaxf(v, 0.f);
                atomicAdd(&hT[(rl / C_CTX) * E_DIM + col], v);
            }
        }
    __syncthreads();

    // write h (bf16) to workspace, coalesced 16B/thread
    {
        int f = t * 8;                 // 2048 elems / 256 threads
        int bl = f >> 8, col = f & 255;
        short8 o;
        #pragma unroll
        for (int j = 0; j < 8; ++j) o[j] = f2bf(hT[f + j]);
        *(short8*)((short*)h_out + ((size_t)(b0 + bl) * E_DIM + col)) = o;
    }
}

// ---------------- Kernel 2: mu = h@U^T + Ub ; sigma = softplus(h@W^T + Wb) ----------
__global__ __launch_bounds__(256, 2)
void k2_heads(const __hip_bfloat16* __restrict__ h, const float* __restrict__ Uw,
              const float* __restrict__ Ub, const float* __restrict__ Ww,
              const float* __restrict__ Wb, float* __restrict__ out, int Bsz)
{
    __shared__ __align__(16) short lA[64 * LP];
    __shared__ __align__(16) short lB[E_DIM * LP];

    const int t = threadIdx.x, wave = t >> 6, lane = t & 63;
    const int b0 = blockIdx.x * 64;
    const int fr = lane & 15, kg = lane >> 4;

    floatx4 acc[4][4];
    #pragma unroll
    for (int mi = 0; mi < 4; ++mi)
        #pragma unroll
        for (int ni = 0; ni < 4; ++ni)
            acc[mi][ni] = (floatx4){0.f, 0.f, 0.f, 0.f};

    for (int k0 = 0; k0 < E_DIM; k0 += 32) {
        __syncthreads();
        // stage A: h rows (already bf16), 64x32 -> one short8 per thread
        {
            int r = t >> 2, ch = t & 3;
            short8 v = *(const short8*)((const short*)h + (size_t)(b0 + r) * E_DIM + k0 + ch * 8);
            *(short8*)&lA[r * LP + ch * 8] = v;
        }
        // stage B: virtual rows 0..127 = U_w, 128..255 = W_w
        for (int s = t; s < E_DIM * 8; s += 256) {
            int e = s >> 3, ch = s & 7;
            const float* src = (e < 128) ? (Uw + (size_t)e * E_DIM) : (Ww + (size_t)(e - 128) * E_DIM);
            float4 v = *(const float4*)(src + k0 + ch * 4);
            short* dst = &lB[e * LP + ch * 4];
            dst[0] = f2bf(v.x); dst[1] = f2bf(v.y); dst[2] = f2bf(v.z); dst[3] = f2bf(v.w);
        }
        __syncthreads();

        short8 bfr[4];
        #pragma unroll
        for (int ni = 0; ni < 4; ++ni)
            bfr[ni] = *(const short8*)&lB[(wave * 64 + ni * 16 + fr) * LP + kg * 8];
        #pragma unroll
        for (int mi = 0; mi < 4; ++mi) {
            short8 afr = *(const short8*)&lA[(mi * 16 + fr) * LP + kg * 8];
            #pragma unroll
            for (int ni = 0; ni < 4; ++ni)
                acc[mi][ni] = __builtin_amdgcn_mfma_f32_16x16x32_bf16(afr, bfr[ni], acc[mi][ni], 0, 0, 0);
        }
    }

    // epilogue: bias + (identity | softplus), write f32 outputs
    #pragma unroll
    for (int mi = 0; mi < 4; ++mi)
        #pragma unroll
        for (int ni = 0; ni < 4; ++ni) {
            int col = wave * 64 + ni * 16 + fr;
            #pragma unroll
            for (int j = 0; j < 4; ++j) {
                int r = b0 + mi * 16 + (lane >> 4) * 4 + j;
                float v = acc[mi][ni][j];
                if (col < 128) {
                    out[(size_t)r * 128 + col] = v + Ub[col];
                } else {
                    float x = v + Wb[col - 128];
                    float sp = fmaxf(x, 0.f) + log1pf(expf(-fabsf(x)));
                    out[(size_t)Bsz * 128 + (size_t)r * 128 + (col - 128)] = sp;
                }
            }
        }
}

extern "C" void kernel_launch(void* const* d_in, const int* in_sizes, int n_in,
                              void* d_out, int out_size, void* d_ws, size_t ws_size,
                              hipStream_t stream)
{
    const int*   tgt = (const int*)d_in[0];
    const int*   ctx = (const int*)d_in[1];
    const float* R   = (const float*)d_in[2];
    const float* Mw  = (const float*)d_in[3];
    const float* Mb  = (const float*)d_in[4];
    const float* Uw  = (const float*)d_in[5];
    const float* Ub  = (const float*)d_in[6];
    const float* Ww  = (const float*)d_in[7];
    const float* Wb  = (const float*)d_in[8];
    float* out = (float*)d_out;
    const int Bsz = in_sizes[0];

    __hip_bfloat16* h = (__hip_bfloat16*)d_ws;  // B x 256 bf16 = 8 MB

    k1_gemm_h<<<Bsz / BB1, 256, 0, stream>>>(tgt, ctx, R, Mw, Mb, h);
    k2_heads<<<Bsz / 64, 256, 0, stream>>>(h, Uw, Ub, Ww, Wb, out, Bsz);
}

// Round 2
// 289.323 us; speedup vs baseline: 1.2345x; 1.2345x over previous
//
#include <hip/hip_runtime.h>
#include <hip/hip_bf16.h>

typedef __attribute__((ext_vector_type(8))) short short8;
typedef __attribute__((ext_vector_type(4))) float floatx4;

static __device__ __forceinline__ short f2bf(float f) {
    union { float f; unsigned u; } v; v.f = f;
    unsigned r = v.u + 0x7fffu + ((v.u >> 16) & 1u);
    return (short)(r >> 16);
}

#define C_CTX 10
#define D_EMB 128
#define E_DIM 256

// ws layout (bytes)
#define OFF_H    0u            // h fragments: 16384*256*2 = 8,388,608
#define OFF_MWF  8388608u      // Mw frags: 8192*16 = 131,072
#define OFF_B2F  8519680u      // U|W frags: 131,072
#define OFF_RB   8650752u      // R bf16: 100000*128*2 = 25,600,000
#define WS_NEED  34250752u

// ---------- prep: swizzle Mw and (Uw|Ww) into bf16 MFMA-fragment order ----------
// frag flat = ((w*8 + kc)*4 + ni)*64 + lane ; e = w*64+ni*16+(lane&15) ; k0 = kc*32+(lane>>4)*8
__global__ void prep_w(const float* __restrict__ Mw, const float* __restrict__ Uw,
                       const float* __restrict__ Ww, short* __restrict__ Mwf,
                       short* __restrict__ B2f)
{
    int flat = blockIdx.x * 256 + threadIdx.x;   // 0..16383
    int which = flat >> 13;                       // 0 = Mwf, 1 = B2f
    int f = flat & 8191;
    int l = f & 63, ni = (f >> 6) & 3, kc = (f >> 8) & 7, w = f >> 11;
    int e = w * 64 + ni * 16 + (l & 15);
    int k0 = kc * 32 + (l >> 4) * 8;
    const float* src;
    if (which == 0)      src = Mw + (size_t)e * E_DIM + k0;
    else if (e < 128)    src = Uw + (size_t)e * E_DIM + k0;
    else                 src = Ww + (size_t)(e - 128) * E_DIM + k0;
    float4 x = *(const float4*)src;
    float4 y = *(const float4*)(src + 4);
    short8 o;
    o[0]=f2bf(x.x); o[1]=f2bf(x.y); o[2]=f2bf(x.z); o[3]=f2bf(x.w);
    o[4]=f2bf(y.x); o[5]=f2bf(y.y); o[6]=f2bf(y.z); o[7]=f2bf(y.w);
    short* dst = (which == 0 ? Mwf : B2f) + (size_t)f * 8;
    *(short8*)dst = o;
}

// ---------- prep: R f32 -> bf16 ----------
__global__ void prep_R(const float* __restrict__ R, short* __restrict__ Rb, int n)
{
    int stride = gridDim.x * blockDim.x * 8;
    for (int i = (blockIdx.x * 256 + threadIdx.x) * 8; i < n; i += stride) {
        float4 x = *(const float4*)(R + i);
        float4 y = *(const float4*)(R + i + 4);
        short8 o;
        o[0]=f2bf(x.x); o[1]=f2bf(x.y); o[2]=f2bf(x.z); o[3]=f2bf(x.w);
        o[4]=f2bf(y.x); o[5]=f2bf(y.y); o[6]=f2bf(y.z); o[7]=f2bf(y.w);
        *(short8*)(Rb + i) = o;
    }
}

// ---------- k1: proj GEMM + bias + relu + segment-sum, h written in frag order ----------
__global__ __launch_bounds__(256, 2)
void k1_gemm_h(const int* __restrict__ tgt, const int* __restrict__ ctx,
               const float* __restrict__ R, const short* __restrict__ Rb, int use_rbf,
               const short* __restrict__ Mwf, const float* __restrict__ Mb,
               short* __restrict__ hws)
{
    __shared__ __align__(16) short lA[2560 * 8];   // 40 KB: A frags [kc(8)][mi(5)][lane(64)] x short8
    __shared__ float hT[2048];                     // 8 x 256 h accumulator
    __shared__ int ids[80];
    __shared__ int tids[8];
    __shared__ float mbs[E_DIM];

    const int t = threadIdx.x, w = t >> 6, l = t & 63;
    const int b0 = blockIdx.x * 8;

    if (t < 80) ids[t] = ctx[b0 * C_CTX + t];
    if (t >= 96 && t < 104) tids[t - 96] = tgt[b0 + (t - 96)];
    mbs[t] = Mb[t];
    for (int i = t; i < 2048; i += 256) hT[i] = 0.f;

    // B fragments, first half (kc 0..3) — issue before staging for overlap
    short8 bfr0[4][4];
    #pragma unroll
    for (int k4 = 0; k4 < 4; ++k4)
        #pragma unroll
        for (int ni = 0; ni < 4; ++ni)
            bfr0[k4][ni] = *(const short8*)(Mwf + ((((size_t)w * 8 + k4) * 4 + ni) * 64 + l) * 8);

    __syncthreads();   // ids/tids visible

    // stage A: 2560 fragment-chunks, lane-linear LDS writes (conflict-free)
    #pragma unroll
    for (int it = 0; it < 10; ++it) {
        int fa = t + it * 256;
        int li = fa & 63, frag = fa >> 6;
        int kc = frag / 5, mi = frag - kc * 5;
        int r = mi * 16 + (li & 15);
        int col = (kc * 4 + (li >> 4)) * 8;
        int rid = (col < D_EMB) ? ids[r] : tids[r / C_CTX];
        int c = (col < D_EMB) ? col : (col - D_EMB);
        short8 v;
        if (use_rbf) {
            v = *(const short8*)(Rb + (size_t)rid * D_EMB + c);
        } else {
            const float* s = R + (size_t)rid * D_EMB + c;
            float4 x = *(const float4*)s;
            float4 y = *(const float4*)(s + 4);
            v[0]=f2bf(x.x); v[1]=f2bf(x.y); v[2]=f2bf(x.z); v[3]=f2bf(x.w);
            v[4]=f2bf(y.x); v[5]=f2bf(y.y); v[6]=f2bf(y.z); v[7]=f2bf(y.w);
        }
        *(short8*)&lA[fa * 8] = v;
    }
    __syncthreads();

    // B fragments, second half
    short8 bfr1[4][4];
    #pragma unroll
    for (int k4 = 0; k4 < 4; ++k4)
        #pragma unroll
        for (int ni = 0; ni < 4; ++ni)
            bfr1[k4][ni] = *(const short8*)(Mwf + ((((size_t)w * 8 + 4 + k4) * 4 + ni) * 64 + l) * 8);

    floatx4 acc[5][4];
    #pragma unroll
    for (int mi = 0; mi < 5; ++mi)
        #pragma unroll
        for (int ni = 0; ni < 4; ++ni)
            acc[mi][ni] = (floatx4){0.f, 0.f, 0.f, 0.f};

    #pragma unroll
    for (int kc = 0; kc < 8; ++kc) {
        #pragma unroll
        for (int mi = 0; mi < 5; ++mi) {
            short8 afr = *(const short8*)&lA[((kc * 5 + mi) * 64 + l) * 8];
            #pragma unroll
            for (int ni = 0; ni < 4; ++ni) {
                short8 b = (kc < 4) ? bfr0[kc][ni] : bfr1[kc - 4][ni];
                acc[mi][ni] = __builtin_amdgcn_mfma_f32_16x16x32_bf16(afr, b, acc[mi][ni], 0, 0, 0);
            }
        }
    }

    // epilogue: +bias, relu, segment-sum over C into hT
    #pragma unroll
    for (int mi = 0; mi < 5; ++mi)
        #pragma unroll
        for (int ni = 0; ni < 4; ++ni) {
            int col = w * 64 + ni * 16 + (l & 15);
            float bias = mbs[col];
            #pragma unroll
            for (int j = 0; j < 4; ++j) {
                int rl = mi * 16 + (l >> 4) * 4 + j;    // 0..79
                float v = acc[mi][ni][j] + bias;
                v = fmaxf(v, 0.f);
                atomicAdd(&hT[(rl / C_CTX) * E_DIM + col], v);
            }
        }
    __syncthreads();

    // write h (bf16) in k2 fragment order
    {
        int f = t * 8;
        int bl = f >> 8, col = f & 255;
        int gr = b0 + bl;
        int b2 = gr >> 6, r6 = gr & 63;
        int mi = r6 >> 4, lr = r6 & 15;
        int kc = col >> 5, sub = (col >> 3) & 3;
        size_t aflat = (((size_t)b2 * 8 + kc) * 4 + mi) * 64 + (sub * 16 + lr);
        short8 o;
        #pragma unroll
        for (int j = 0; j < 8; ++j) o[j] = f2bf(hT[f + j]);
        *(short8*)(hws + aflat * 8) = o;
    }
}

// ---------- k2: pure-register GEMM, mu | softplus(sigma) ----------
__global__ __launch_bounds__(256, 2)
void k2_heads(const short* __restrict__ hws, const short* __restrict__ B2f,
              const float* __restrict__ Ub, const float* __restrict__ Wb,
              float* __restrict__ out, int Bsz)
{
    const int t = threadIdx.x, w = t >> 6, l = t & 63;
    const int b2 = blockIdx.x, b0 = b2 * 64;

    floatx4 acc[4][4];
    #pragma unroll
    for (int mi = 0; mi < 4; ++mi)
        #pragma unroll
        for (int ni = 0; ni < 4; ++ni)
            acc[mi][ni] = (floatx4){0.f, 0.f, 0.f, 0.f};

    #pragma unroll
    for (int kc = 0; kc < 8; ++kc) {
        short8 afr[4], bfr[4];
        #pragma unroll
        for (int mi = 0; mi < 4; ++mi)
            afr[mi] = *(const short8*)(hws + ((((size_t)b2 * 8 + kc) * 4 + mi) * 64 + l) * 8);
        #pragma unroll
        for (int ni = 0; ni < 4; ++ni)
            bfr[ni] = *(const short8*)(B2f + ((((size_t)w * 8 + kc) * 4 + ni) * 64 + l) * 8);
        #pragma unroll
        for (int mi = 0; mi < 4; ++mi)
            #pragma unroll
            for (int ni = 0; ni < 4; ++ni)
                acc[mi][ni] = __builtin_amdgcn_mfma_f32_16x16x32_bf16(afr[mi], bfr[ni], acc[mi][ni], 0, 0, 0);
    }

    #pragma unroll
    for (int mi = 0; mi < 4; ++mi)
        #pragma unroll
        for (int ni = 0; ni < 4; ++ni) {
            int col = w * 64 + ni * 16 + (l & 15);
            #pragma unroll
            for (int j = 0; j < 4; ++j) {
                int r = b0 + mi * 16 + (l >> 4) * 4 + j;
                float v = acc[mi][ni][j];
                if (col < 128) {
                    out[(size_t)r * 128 + col] = v + Ub[col];
                } else {
                    float x = v + Wb[col - 128];
                    float sp = fmaxf(x, 0.f) + log1pf(expf(-fabsf(x)));
                    out[(size_t)Bsz * 128 + (size_t)r * 128 + (col - 128)] = sp;
                }
            }
        }
}

extern "C" void kernel_launch(void* const* d_in, const int* in_sizes, int n_in,
                              void* d_out, int out_size, void* d_ws, size_t ws_size,
                              hipStream_t stream)
{
    const int*   tgt = (const int*)d_in[0];
    const int*   ctx = (const int*)d_in[1];
    const float* R   = (const float*)d_in[2];
    const float* Mw  = (const float*)d_in[3];
    const float* Mb  = (const float*)d_in[4];
    const float* Uw  = (const float*)d_in[5];
    const float* Ub  = (const float*)d_in[6];
    const float* Ww  = (const float*)d_in[7];
    const float* Wb  = (const float*)d_in[8];
    float* out = (float*)d_out;
    const int Bsz = in_sizes[0];
    const int Vn  = in_sizes[2] / D_EMB;   // 100000

    char* ws = (char*)d_ws;
    short* hws = (short*)(ws + OFF_H);
    short* Mwf = (short*)(ws + OFF_MWF);
    short* B2f = (short*)(ws + OFF_B2F);
    short* Rb  = (short*)(ws + OFF_RB);
    int use_rbf = (ws_size >= (size_t)WS_NEED) ? 1 : 0;

    prep_w<<<64, 256, 0, stream>>>(Mw, Uw, Ww, Mwf, B2f);
    if (use_rbf)
        prep_R<<<2048, 256, 0, stream>>>(R, Rb, Vn * D_EMB);

    k1_gemm_h<<<Bsz / 8, 256, 0, stream>>>(tgt, ctx, R, Rb, use_rbf, Mwf, Mb, hws);
    k2_heads<<<Bsz / 64, 256, 0, stream>>>(hws, B2f, Ub, Wb, out, Bsz);
}

// Round 3
// 100.955 us; speedup vs baseline: 3.5378x; 2.8658x over previous
//
#include <hip/hip_runtime.h>
#include <hip/hip_bf16.h>

typedef __attribute__((ext_vector_type(8))) short short8;
typedef __attribute__((ext_vector_type(4))) float floatx4;

static __device__ __forceinline__ short f2bf(float f) {
    union { float f; unsigned u; } v; v.f = f;
    unsigned r = v.u + 0x7fffu + ((v.u >> 16) & 1u);
    return (short)(r >> 16);
}
static __device__ __forceinline__ float bf2f(short s) {
    union { unsigned u; float f; } v; v.u = ((unsigned)(unsigned short)s) << 16;
    return v.f;
}

#define C_CTX 10
#define D_EMB 128
#define E_DIM 256

// ==================== PRIMARY PATH ====================
// G = R @ M1^T, T = R @ M2^T (V x 256 each, bf16), then
// h[b] = sum_c relu(G[ctx[b,c]] + T[tgt[b]] + Mb), then heads.

// ---- prep: build bf16 MFMA B-fragments for M1, M2 (K=128) and U|W (K=256) ----
__global__ void prep_main(const float* __restrict__ Mw, const float* __restrict__ Uw,
                          const float* __restrict__ Ww, short* __restrict__ M1f,
                          short* __restrict__ M2f, short* __restrict__ B2f)
{
    int u = blockIdx.x * 256 + threadIdx.x;   // 0..16383
    const float* src;
    short* dst;
    if (u < 8192) {
        int f = u & 4095;
        int l = f & 63, kc = (f >> 6) & 3, grp = f >> 8;     // grp 0..15
        int e = grp * 16 + (l & 15);
        int k = kc * 32 + (l >> 4) * 8 + ((u < 4096) ? 0 : 128);
        src = Mw + (size_t)e * E_DIM + k;
        dst = ((u < 4096) ? M1f : M2f) + (size_t)f * 8;
    } else {
        int f = u - 8192;
        int l = f & 63, ni = (f >> 6) & 3, kc = (f >> 8) & 7, w = f >> 11;
        int e = w * 64 + ni * 16 + (l & 15);
        int k = kc * 32 + (l >> 4) * 8;
        src = (e < 128) ? (Uw + (size_t)e * E_DIM + k)
                        : (Ww + (size_t)(e - 128) * E_DIM + k);
        dst = B2f + (size_t)f * 8;
    }
    float4 x = *(const float4*)src;
    float4 y = *(const float4*)(src + 4);
    short8 o;
    o[0]=f2bf(x.x); o[1]=f2bf(x.y); o[2]=f2bf(x.z); o[3]=f2bf(x.w);
    o[4]=f2bf(y.x); o[5]=f2bf(y.y); o[6]=f2bf(y.z); o[7]=f2bf(y.w);
    *(short8*)dst = o;
}

// ---- k_gt: streaming GEMM, 64 rows x 512 cols (G|T) x K=128 per block ----
__global__ __launch_bounds__(256, 2)
void k_gt(const float* __restrict__ R, const short* __restrict__ M1f,
          const short* __restrict__ M2f, short* __restrict__ G,
          short* __restrict__ T, int V)
{
    __shared__ __align__(16) short buf[64 * 520];   // 66.5 KB; first 16 KB = A frags
    const int t = threadIdx.x, w = t >> 6, l = t & 63;
    const int r0 = blockIdx.x * 64;

    // stage A fragments (frag-linear, conflict-free): 1024 short8 units
    #pragma unroll
    for (int i = 0; i < 4; ++i) {
        int fa = t + i * 256;
        int li = fa & 63, frag = fa >> 6;
        int kc = frag >> 2, mi = frag & 3;
        int r = mi * 16 + (li & 15);
        int k = kc * 32 + (li >> 4) * 8;
        int gr = r0 + r; if (gr >= V) gr = V - 1;
        const float* s = R + (size_t)gr * D_EMB + k;
        float4 x = *(const float4*)s;
        float4 y = *(const float4*)(s + 4);
        short8 v;
        v[0]=f2bf(x.x); v[1]=f2bf(x.y); v[2]=f2bf(x.z); v[3]=f2bf(x.w);
        v[4]=f2bf(y.x); v[5]=f2bf(y.y); v[6]=f2bf(y.z); v[7]=f2bf(y.w);
        *(short8*)&buf[fa * 8] = v;
    }
    __syncthreads();

    const short* Bf = (w < 2) ? M1f : M2f;   // waves 0,1 -> G; 2,3 -> T
    const int g0 = (w & 1) * 8;              // col-group base within matrix

    floatx4 acc[4][8];
    #pragma unroll
    for (int mi = 0; mi < 4; ++mi)
        #pragma unroll
        for (int n = 0; n < 8; ++n)
            acc[mi][n] = (floatx4){0.f, 0.f, 0.f, 0.f};

    #pragma unroll
    for (int kc = 0; kc < 4; ++kc) {
        short8 bfr[8];
        #pragma unroll
        for (int n = 0; n < 8; ++n)
            bfr[n] = *(const short8*)(Bf + (((size_t)(g0 + n) * 4 + kc) * 64 + l) * 8);
        short8 afr[4];
        #pragma unroll
        for (int mi = 0; mi < 4; ++mi)
            afr[mi] = *(const short8*)&buf[((kc * 4 + mi) * 64 + l) * 8];
        #pragma unroll
        for (int mi = 0; mi < 4; ++mi)
            #pragma unroll
            for (int n = 0; n < 8; ++n)
                acc[mi][n] = __builtin_amdgcn_mfma_f32_16x16x32_bf16(afr[mi], bfr[n], acc[mi][n], 0, 0, 0);
    }
    __syncthreads();   // A-frag region dead; safe to overwrite

    // transpose acc -> row-major [64][520] (padded: rows shift banks, 2-way max)
    #pragma unroll
    for (int mi = 0; mi < 4; ++mi)
        #pragma unroll
        for (int n = 0; n < 8; ++n) {
            int col = w * 128 + n * 16 + (l & 15);
            #pragma unroll
            for (int j = 0; j < 4; ++j) {
                int row = mi * 16 + (l >> 4) * 4 + j;
                buf[row * 520 + col] = f2bf(acc[mi][n][j]);
            }
        }
    __syncthreads();

    // coalesced bf16 stores: 4096 short8 units
    #pragma unroll
    for (int i = 0; i < 16; ++i) {
        int u = t + i * 256;
        int row = u >> 6, c8 = (u & 63) * 8;
        int gr = r0 + row;
        if (gr < V) {
            short8 v = *(const short8*)&buf[row * 520 + c8];
            short* dst = (c8 < 256) ? (G + (size_t)gr * 256 + c8)
                                    : (T + (size_t)gr * 256 + (c8 - 256));
            *(short8*)dst = v;
        }
    }
}

// ---- k_h: h[b] = sum_c relu(G[ctx] + T[tgt] + Mb), written in k2 frag order ----
__global__ __launch_bounds__(256, 4)
void k_h(const int* __restrict__ tgt, const int* __restrict__ ctx,
         const short* __restrict__ G, const short* __restrict__ T,
         const float* __restrict__ Mb, short* __restrict__ hws)
{
    __shared__ int ids[80];
    __shared__ int tids[8];
    __shared__ float mbv[E_DIM];
    const int t = threadIdx.x, w = t >> 6, l = t & 63;
    const int b0 = blockIdx.x * 8;
    if (t < 80) ids[t] = ctx[b0 * C_CTX + t];
    if (t >= 96 && t < 104) tids[t - 96] = tgt[b0 + t - 96];
    mbv[t] = Mb[t];
    __syncthreads();

    const int bl = w * 2 + (l >> 5);      // 0..7 local b
    const int c8 = (l & 31) * 8;          // col base, half-wave covers 256 cols
    float tv[8], acc[8];
    short8 tr = *(const short8*)(T + (size_t)tids[bl] * 256 + c8);
    #pragma unroll
    for (int j = 0; j < 8; ++j) { tv[j] = bf2f(tr[j]) + mbv[c8 + j]; acc[j] = 0.f; }

    #pragma unroll
    for (int c = 0; c < C_CTX; ++c) {
        short8 g = *(const short8*)(G + (size_t)ids[bl * C_CTX + c] * 256 + c8);
        #pragma unroll
        for (int j = 0; j < 8; ++j)
            acc[j] += fmaxf(bf2f(g[j]) + tv[j], 0.f);
    }

    int gr = b0 + bl;
    int b2 = gr >> 6, r6 = gr & 63, mi = r6 >> 4, lr = r6 & 15;
    int kc = c8 >> 5, sub = (c8 >> 3) & 3;
    size_t aflat = (((size_t)b2 * 8 + kc) * 4 + mi) * 64 + (sub * 16 + lr);
    short8 o;
    #pragma unroll
    for (int j = 0; j < 8; ++j) o[j] = f2bf(acc[j]);
    *(short8*)(hws + aflat * 8) = o;
}

// ---- k2: pure-register GEMM, mu | softplus(sigma) (shared by both paths) ----
__global__ __launch_bounds__(256, 2)
void k2_heads(const short* __restrict__ hws, const short* __restrict__ B2f,
              const float* __restrict__ Ub, const float* __restrict__ Wb,
              float* __restrict__ out, int Bsz)
{
    const int t = threadIdx.x, w = t >> 6, l = t & 63;
    const int b2 = blockIdx.x, b0 = b2 * 64;

    floatx4 acc[4][4];
    #pragma unroll
    for (int mi = 0; mi < 4; ++mi)
        #pragma unroll
        for (int ni = 0; ni < 4; ++ni)
            acc[mi][ni] = (floatx4){0.f, 0.f, 0.f, 0.f};

    #pragma unroll
    for (int kc = 0; kc < 8; ++kc) {
        short8 afr[4], bfr[4];
        #pragma unroll
        for (int mi = 0; mi < 4; ++mi)
            afr[mi] = *(const short8*)(hws + ((((size_t)b2 * 8 + kc) * 4 + mi) * 64 + l) * 8);
        #pragma unroll
        for (int ni = 0; ni < 4; ++ni)
            bfr[ni] = *(const short8*)(B2f + ((((size_t)w * 8 + kc) * 4 + ni) * 64 + l) * 8);
        #pragma unroll
        for (int mi = 0; mi < 4; ++mi)
            #pragma unroll
            for (int ni = 0; ni < 4; ++ni)
                acc[mi][ni] = __builtin_amdgcn_mfma_f32_16x16x32_bf16(afr[mi], bfr[ni], acc[mi][ni], 0, 0, 0);
    }

    #pragma unroll
    for (int mi = 0; mi < 4; ++mi)
        #pragma unroll
        for (int ni = 0; ni < 4; ++ni) {
            int col = w * 64 + ni * 16 + (l & 15);
            #pragma unroll
            for (int j = 0; j < 4; ++j) {
                int r = b0 + mi * 16 + (l >> 4) * 4 + j;
                float v = acc[mi][ni][j];
                if (col < 128) {
                    out[(size_t)r * 128 + col] = v + Ub[col];
                } else {
                    float x = v + Wb[col - 128];
                    float sp = fmaxf(x, 0.f) + log1pf(expf(-fabsf(x)));
                    out[(size_t)Bsz * 128 + (size_t)r * 128 + (col - 128)] = sp;
                }
            }
        }
}

// ==================== FALLBACK PATH (verified R2 code) ====================
#define FB_OFF_H    0u
#define FB_OFF_MWF  8388608u
#define FB_OFF_B2F  8519680u
#define FB_OFF_RB   8650752u
#define FB_WS_NEED  34250752u

__global__ void prep_w_fb(const float* __restrict__ Mw, const float* __restrict__ Uw,
                          const float* __restrict__ Ww, short* __restrict__ Mwf,
                          short* __restrict__ B2f)
{
    int flat = blockIdx.x * 256 + threadIdx.x;
    int which = flat >> 13;
    int f = flat & 8191;
    int l = f & 63, ni = (f >> 6) & 3, kc = (f >> 8) & 7, w = f >> 11;
    int e = w * 64 + ni * 16 + (l & 15);
    int k0 = kc * 32 + (l >> 4) * 8;
    const float* src;
    if (which == 0)      src = Mw + (size_t)e * E_DIM + k0;
    else if (e < 128)    src = Uw + (size_t)e * E_DIM + k0;
    else                 src = Ww + (size_t)(e - 128) * E_DIM + k0;
    float4 x = *(const float4*)src;
    float4 y = *(const float4*)(src + 4);
    short8 o;
    o[0]=f2bf(x.x); o[1]=f2bf(x.y); o[2]=f2bf(x.z); o[3]=f2bf(x.w);
    o[4]=f2bf(y.x); o[5]=f2bf(y.y); o[6]=f2bf(y.z); o[7]=f2bf(y.w);
    short* dst = (which == 0 ? Mwf : B2f) + (size_t)f * 8;
    *(short8*)dst = o;
}

__global__ void prep_R_fb(const float* __restrict__ R, short* __restrict__ Rb, int n)
{
    int stride = gridDim.x * blockDim.x * 8;
    for (int i = (blockIdx.x * 256 + threadIdx.x) * 8; i < n; i += stride) {
        float4 x = *(const float4*)(R + i);
        float4 y = *(const float4*)(R + i + 4);
        short8 o;
        o[0]=f2bf(x.x); o[1]=f2bf(x.y); o[2]=f2bf(x.z); o[3]=f2bf(x.w);
        o[4]=f2bf(y.x); o[5]=f2bf(y.y); o[6]=f2bf(y.z); o[7]=f2bf(y.w);
        *(short8*)(Rb + i) = o;
    }
}

__global__ __launch_bounds__(256, 2)
void k1_fb(const int* __restrict__ tgt, const int* __restrict__ ctx,
           const float* __restrict__ R, const short* __restrict__ Rb, int use_rbf,
           const short* __restrict__ Mwf, const float* __restrict__ Mb,
           short* __restrict__ hws)
{
    __shared__ __align__(16) short lA[2560 * 8];
    __shared__ float hT[2048];
    __shared__ int ids[80];
    __shared__ int tids[8];
    __shared__ float mbs[E_DIM];

    const int t = threadIdx.x, w = t >> 6, l = t & 63;
    const int b0 = blockIdx.x * 8;

    if (t < 80) ids[t] = ctx[b0 * C_CTX + t];
    if (t >= 96 && t < 104) tids[t - 96] = tgt[b0 + (t - 96)];
    mbs[t] = Mb[t];
    for (int i = t; i < 2048; i += 256) hT[i] = 0.f;

    short8 bfr0[4][4];
    #pragma unroll
    for (int k4 = 0; k4 < 4; ++k4)
        #pragma unroll
        for (int ni = 0; ni < 4; ++ni)
            bfr0[k4][ni] = *(const short8*)(Mwf + ((((size_t)w * 8 + k4) * 4 + ni) * 64 + l) * 8);

    __syncthreads();

    #pragma unroll
    for (int it = 0; it < 10; ++it) {
        int fa = t + it * 256;
        int li = fa & 63, frag = fa >> 6;
        int kc = frag / 5, mi = frag - kc * 5;
        int r = mi * 16 + (li & 15);
        int col = (kc * 4 + (li >> 4)) * 8;
        int rid = (col < D_EMB) ? ids[r] : tids[r / C_CTX];
        int c = (col < D_EMB) ? col : (col - D_EMB);
        short8 v;
        if (use_rbf) {
            v = *(const short8*)(Rb + (size_t)rid * D_EMB + c);
        } else {
            const float* s = R + (size_t)rid * D_EMB + c;
            float4 x = *(const float4*)s;
            float4 y = *(const float4*)(s + 4);
            v[0]=f2bf(x.x); v[1]=f2bf(x.y); v[2]=f2bf(x.z); v[3]=f2bf(x.w);
            v[4]=f2bf(y.x); v[5]=f2bf(y.y); v[6]=f2bf(y.z); v[7]=f2bf(y.w);
        }
        *(short8*)&lA[fa * 8] = v;
    }
    __syncthreads();

    short8 bfr1[4][4];
    #pragma unroll
    for (int k4 = 0; k4 < 4; ++k4)
        #pragma unroll
        for (int ni = 0; ni < 4; ++ni)
            bfr1[k4][ni] = *(const short8*)(Mwf + ((((size_t)w * 8 + 4 + k4) * 4 + ni) * 64 + l) * 8);

    floatx4 acc[5][4];
    #pragma unroll
    for (int mi = 0; mi < 5; ++mi)
        #pragma unroll
        for (int ni = 0; ni < 4; ++ni)
            acc[mi][ni] = (floatx4){0.f, 0.f, 0.f, 0.f};

    #pragma unroll
    for (int kc = 0; kc < 8; ++kc) {
        #pragma unroll
        for (int mi = 0; mi < 5; ++mi) {
            short8 afr = *(const short8*)&lA[((kc * 5 + mi) * 64 + l) * 8];
            #pragma unroll
            for (int ni = 0; ni < 4; ++ni) {
                short8 b = (kc < 4) ? bfr0[kc][ni] : bfr1[kc - 4][ni];
                acc[mi][ni] = __builtin_amdgcn_mfma_f32_16x16x32_bf16(afr, b, acc[mi][ni], 0, 0, 0);
            }
        }
    }

    #pragma unroll
    for (int mi = 0; mi < 5; ++mi)
        #pragma unroll
        for (int ni = 0; ni < 4; ++ni) {
            int col = w * 64 + ni * 16 + (l & 15);
            float bias = mbs[col];
            #pragma unroll
            for (int j = 0; j < 4; ++j) {
                int rl = mi * 16 + (l >> 4) * 4 + j;
                float v = acc[mi][ni][j] + bias;
                v = fmaxf(v, 0.f);
                atomicAdd(&hT[(rl / C_CTX) * E_DIM + col], v);
            }
        }
    __syncthreads();

    {
        int f = t * 8;
        int bl = f >> 8, col = f & 255;
        int gr = b0 + bl;
        int b2 = gr >> 6, r6 = gr & 63;
        int mi = r6 >> 4, lr = r6 & 15;
        int kc = col >> 5, sub = (col >> 3) & 3;
        size_t aflat = (((size_t)b2 * 8 + kc) * 4 + mi) * 64 + (sub * 16 + lr);
        short8 o;
        #pragma unroll
        for (int j = 0; j < 8; ++j) o[j] = f2bf(hT[f + j]);
        *(short8*)(hws + aflat * 8) = o;
    }
}

// ==================== launch ====================
extern "C" void kernel_launch(void* const* d_in, const int* in_sizes, int n_in,
                              void* d_out, int out_size, void* d_ws, size_t ws_size,
                              hipStream_t stream)
{
    const int*   tgt = (const int*)d_in[0];
    const int*   ctx = (const int*)d_in[1];
    const float* R   = (const float*)d_in[2];
    const float* Mw  = (const float*)d_in[3];
    const float* Mb  = (const float*)d_in[4];
    const float* Uw  = (const float*)d_in[5];
    const float* Ub  = (const float*)d_in[6];
    const float* Ww  = (const float*)d_in[7];
    const float* Wb  = (const float*)d_in[8];
    float* out = (float*)d_out;
    const int Bsz = in_sizes[0];
    const int Vn  = in_sizes[2] / D_EMB;

    char* ws = (char*)d_ws;
    size_t offG   = 0;
    size_t offT   = (size_t)Vn * 512;
    size_t offH   = offT + (size_t)Vn * 512;
    size_t offM1f = offH + (size_t)Bsz * 512;
    size_t offM2f = offM1f + 65536;
    size_t offB2f = offM2f + 65536;
    size_t need   = offB2f + 131072;

    if (ws_size >= need) {
        short* G   = (short*)(ws + offG);
        short* T   = (short*)(ws + offT);
        short* hws = (short*)(ws + offH);
        short* M1f = (short*)(ws + offM1f);
        short* M2f = (short*)(ws + offM2f);
        short* B2f = (short*)(ws + offB2f);

        prep_main<<<64, 256, 0, stream>>>(Mw, Uw, Ww, M1f, M2f, B2f);
        k_gt<<<(Vn + 63) / 64, 256, 0, stream>>>(R, M1f, M2f, G, T, Vn);
        k_h<<<Bsz / 8, 256, 0, stream>>>(tgt, ctx, G, T, Mb, hws);
        k2_heads<<<Bsz / 64, 256, 0, stream>>>(hws, B2f, Ub, Wb, out, Bsz);
    } else {
        short* hws = (short*)(ws + FB_OFF_H);
        short* Mwf = (short*)(ws + FB_OFF_MWF);
        short* B2f = (short*)(ws + FB_OFF_B2F);
        short* Rb  = (short*)(ws + FB_OFF_RB);
        int use_rbf = (ws_size >= (size_t)FB_WS_NEED) ? 1 : 0;

        prep_w_fb<<<64, 256, 0, stream>>>(Mw, Uw, Ww, Mwf, B2f);
        if (use_rbf)
            prep_R_fb<<<2048, 256, 0, stream>>>(R, Rb, Vn * D_EMB);
        k1_fb<<<Bsz / 8, 256, 0, stream>>>(tgt, ctx, R, Rb, use_rbf, Mwf, Mb, hws);
        k2_heads<<<Bsz / 64, 256, 0, stream>>>(hws, B2f, Ub, Wb, out, Bsz);
    }
}

// Round 4
// 86.390 us; speedup vs baseline: 4.1343x; 1.1686x over previous
//
#include <hip/hip_runtime.h>
#include <hip/hip_bf16.h>

typedef __attribute__((ext_vector_type(8))) short short8;
typedef __attribute__((ext_vector_type(4))) float floatx4;

static __device__ __forceinline__ short f2bf(float f) {
    union { float f; unsigned u; } v; v.f = f;
    unsigned r = v.u + 0x7fffu + ((v.u >> 16) & 1u);
    return (short)(r >> 16);
}
static __device__ __forceinline__ float bf2f(short s) {
    union { unsigned u; float f; } v; v.u = ((unsigned)(unsigned short)s) << 16;
    return v.f;
}

#define C_CTX 10
#define D_EMB 128
#define E_DIM 256

// ---- prep: bf16 MFMA B-fragments for M1 (cols 0:128 of Mw), M2 (cols 128:256), U|W ----
// M1f/M2f frag: ((grp*4 + kc)*64 + l)*8 ; e = grp*16+(l&15) ; k = kc*32+(l>>4)*8
// B2f   frag:   (((w*8 + kc)*4 + ni)*64 + l)*8 ; e = w*64+ni*16+(l&15) ; k = kc*32+(l>>4)*8
__global__ void prep_main(const float* __restrict__ Mw, const float* __restrict__ Uw,
                          const float* __restrict__ Ww, short* __restrict__ M1f,
                          short* __restrict__ M2f, short* __restrict__ B2f)
{
    int u = blockIdx.x * 256 + threadIdx.x;   // 0..16383
    const float* src;
    short* dst;
    if (u < 8192) {
        int f = u & 4095;
        int l = f & 63, kc = (f >> 6) & 3, grp = f >> 8;     // grp 0..15
        int e = grp * 16 + (l & 15);
        int k = kc * 32 + (l >> 4) * 8 + ((u < 4096) ? 0 : 128);
        src = Mw + (size_t)e * E_DIM + k;
        dst = ((u < 4096) ? M1f : M2f) + (size_t)f * 8;
    } else {
        int f = u - 8192;
        int l = f & 63, ni = (f >> 6) & 3, kc = (f >> 8) & 7, w = f >> 11;
        int e = w * 64 + ni * 16 + (l & 15);
        int k = kc * 32 + (l >> 4) * 8;
        src = (e < 128) ? (Uw + (size_t)e * E_DIM + k)
                        : (Ww + (size_t)(e - 128) * E_DIM + k);
        dst = B2f + (size_t)f * 8;
    }
    float4 x = *(const float4*)src;
    float4 y = *(const float4*)(src + 4);
    short8 o;
    o[0]=f2bf(x.x); o[1]=f2bf(x.y); o[2]=f2bf(x.z); o[3]=f2bf(x.w);
    o[4]=f2bf(y.x); o[5]=f2bf(y.y); o[6]=f2bf(y.z); o[7]=f2bf(y.w);
    *(short8*)dst = o;
}

// ---- k_g: G = R @ M1^T (V x 256, bf16), streaming ----
__global__ __launch_bounds__(256, 3)
void k_g(const float* __restrict__ R, const short* __restrict__ M1f,
         short* __restrict__ G, int V)
{
    __shared__ __align__(16) short buf[64 * 264];   // 33 KB; first 16 KB doubles as A-frag stage
    const int t = threadIdx.x, w = t >> 6, l = t & 63;
    const int r0 = blockIdx.x * 64;

    // stage A fragments (frag-linear, conflict-free): 1024 short8 units
    #pragma unroll
    for (int i = 0; i < 4; ++i) {
        int fa = t + i * 256;
        int li = fa & 63, frag = fa >> 6;     // 0..15
        int kc = frag >> 2, mi = frag & 3;
        int r = mi * 16 + (li & 15);
        int k = kc * 32 + (li >> 4) * 8;
        int gr = r0 + r; if (gr >= V) gr = V - 1;
        const float* s = R + (size_t)gr * D_EMB + k;
        float4 x = *(const float4*)s;
        float4 y = *(const float4*)(s + 4);
        short8 v;
        v[0]=f2bf(x.x); v[1]=f2bf(x.y); v[2]=f2bf(x.z); v[3]=f2bf(x.w);
        v[4]=f2bf(y.x); v[5]=f2bf(y.y); v[6]=f2bf(y.z); v[7]=f2bf(y.w);
        *(short8*)&buf[fa * 8] = v;
    }
    __syncthreads();

    floatx4 acc[4][4];
    #pragma unroll
    for (int mi = 0; mi < 4; ++mi)
        #pragma unroll
        for (int ni = 0; ni < 4; ++ni)
            acc[mi][ni] = (floatx4){0.f, 0.f, 0.f, 0.f};

    #pragma unroll
    for (int kc = 0; kc < 4; ++kc) {
        short8 afr[4], bfr[4];
        #pragma unroll
        for (int mi = 0; mi < 4; ++mi)
            afr[mi] = *(const short8*)&buf[((kc * 4 + mi) * 64 + l) * 8];
        #pragma unroll
        for (int ni = 0; ni < 4; ++ni)
            bfr[ni] = *(const short8*)(M1f + (((size_t)(w * 4 + ni) * 4 + kc) * 64 + l) * 8);
        #pragma unroll
        for (int mi = 0; mi < 4; ++mi)
            #pragma unroll
            for (int ni = 0; ni < 4; ++ni)
                acc[mi][ni] = __builtin_amdgcn_mfma_f32_16x16x32_bf16(afr[mi], bfr[ni], acc[mi][ni], 0, 0, 0);
    }
    __syncthreads();   // A-frag region dead

    // transpose acc -> row-major [64][264]
    #pragma unroll
    for (int mi = 0; mi < 4; ++mi)
        #pragma unroll
        for (int ni = 0; ni < 4; ++ni) {
            int col = w * 64 + ni * 16 + (l & 15);
            #pragma unroll
            for (int j = 0; j < 4; ++j) {
                int row = mi * 16 + (l >> 4) * 4 + j;
                buf[row * 264 + col] = f2bf(acc[mi][ni][j]);
            }
        }
    __syncthreads();

    // coalesced stores: 2048 short8 units
    #pragma unroll
    for (int i = 0; i < 8; ++i) {
        int u = t + i * 256;
        int row = u >> 5, c8 = (u & 31) * 8;
        int gr = r0 + row;
        if (gr < V)
            *(short8*)(G + (size_t)gr * 256 + c8) = *(const short8*)&buf[row * 264 + c8];
    }
}

// ---- k_t: Tt[b] = R[tgt[b]] @ M2^T + Mb  (B x 256, f32) ----
__global__ __launch_bounds__(256, 4)
void k_t(const int* __restrict__ tgt, const float* __restrict__ R,
         const short* __restrict__ M2f, const float* __restrict__ Mb,
         float* __restrict__ Tt)
{
    __shared__ __align__(16) short lA[1024 * 8];   // 16 KB A frags
    __shared__ int tids[64];
    const int t = threadIdx.x, w = t >> 6, l = t & 63;
    const int r0 = blockIdx.x * 64;

    if (t < 64) tids[t] = tgt[r0 + t];
    __syncthreads();

    #pragma unroll
    for (int i = 0; i < 4; ++i) {
        int fa = t + i * 256;
        int li = fa & 63, frag = fa >> 6;
        int kc = frag >> 2, mi = frag & 3;
        int r = mi * 16 + (li & 15);
        int k = kc * 32 + (li >> 4) * 8;
        const float* s = R + (size_t)tids[r] * D_EMB + k;
        float4 x = *(const float4*)s;
        float4 y = *(const float4*)(s + 4);
        short8 v;
        v[0]=f2bf(x.x); v[1]=f2bf(x.y); v[2]=f2bf(x.z); v[3]=f2bf(x.w);
        v[4]=f2bf(y.x); v[5]=f2bf(y.y); v[6]=f2bf(y.z); v[7]=f2bf(y.w);
        *(short8*)&lA[fa * 8] = v;
    }
    __syncthreads();

    floatx4 acc[4][4];
    #pragma unroll
    for (int mi = 0; mi < 4; ++mi)
        #pragma unroll
        for (int ni = 0; ni < 4; ++ni)
            acc[mi][ni] = (floatx4){0.f, 0.f, 0.f, 0.f};

    #pragma unroll
    for (int kc = 0; kc < 4; ++kc) {
        short8 afr[4], bfr[4];
        #pragma unroll
        for (int mi = 0; mi < 4; ++mi)
            afr[mi] = *(const short8*)&lA[((kc * 4 + mi) * 64 + l) * 8];
        #pragma unroll
        for (int ni = 0; ni < 4; ++ni)
            bfr[ni] = *(const short8*)(M2f + (((size_t)(w * 4 + ni) * 4 + kc) * 64 + l) * 8);
        #pragma unroll
        for (int mi = 0; mi < 4; ++mi)
            #pragma unroll
            for (int ni = 0; ni < 4; ++ni)
                acc[mi][ni] = __builtin_amdgcn_mfma_f32_16x16x32_bf16(afr[mi], bfr[ni], acc[mi][ni], 0, 0, 0);
    }

    #pragma unroll
    for (int mi = 0; mi < 4; ++mi)
        #pragma unroll
        for (int ni = 0; ni < 4; ++ni) {
            int col = w * 64 + ni * 16 + (l & 15);
            float mb = Mb[col];
            #pragma unroll
            for (int j = 0; j < 4; ++j) {
                int row = mi * 16 + (l >> 4) * 4 + j;
                Tt[(size_t)(r0 + row) * E_DIM + col] = acc[mi][ni][j] + mb;
            }
        }
}

// ---- k_hh: h = sum_c relu(G[ctx] + Tt) -> LDS frags -> heads GEMM -> out ----
// LDS frag layout with XOR swizzle: element (q = kc*4+mi, s = sub*16+lr)
// stored at hfr[(q*64 + (s ^ kc)) * 8 ..], conflict-free both sides.
__global__ __launch_bounds__(256, 4)
void k_hh(const int* __restrict__ ctx, const short* __restrict__ G,
          const float* __restrict__ Tt, const short* __restrict__ B2f,
          const float* __restrict__ Ub, const float* __restrict__ Wb,
          float* __restrict__ out, int Bsz)
{
    __shared__ __align__(16) short hfr[32 * 64 * 8];   // 32 KB
    __shared__ int ids[64 * C_CTX];
    const int t = threadIdx.x, w = t >> 6, l = t & 63;
    const int b0 = blockIdx.x * 64;

    for (int i = t; i < 64 * C_CTX; i += 256) ids[i] = ctx[(size_t)b0 * C_CTX + i];
    __syncthreads();

    const int hw = l >> 5;               // half-wave
    const int i5 = l & 31;
    const int kcc = i5 & 7, sub = i5 >> 3;
    const int c8 = kcc * 32 + sub * 8;   // col base (permuted across half-wave)

    #pragma unroll
    for (int p = 0; p < 8; ++p) {
        int bl = p * 8 + w * 2 + hw;     // local row 0..63
        const float* tp = Tt + (size_t)(b0 + bl) * E_DIM + c8;
        float4 x = *(const float4*)tp;
        float4 y = *(const float4*)(tp + 4);
        float tv[8] = {x.x, x.y, x.z, x.w, y.x, y.y, y.z, y.w};
        float acc[8] = {0.f, 0.f, 0.f, 0.f, 0.f, 0.f, 0.f, 0.f};
        #pragma unroll
        for (int c = 0; c < C_CTX; ++c) {
            short8 g = *(const short8*)(G + (size_t)ids[bl * C_CTX + c] * E_DIM + c8);
            #pragma unroll
            for (int j = 0; j < 8; ++j)
                acc[j] += fmaxf(bf2f(g[j]) + tv[j], 0.f);
        }
        int mi = bl >> 4, lr = bl & 15;
        int q = kcc * 4 + mi;
        int sp = (sub * 16 + lr) ^ kcc;
        short8 o;
        #pragma unroll
        for (int j = 0; j < 8; ++j) o[j] = f2bf(acc[j]);
        *(short8*)&hfr[(q * 64 + sp) * 8] = o;
    }
    __syncthreads();

    // heads GEMM: 64 rows x 256 cols x K=256
    floatx4 acc2[4][4];
    #pragma unroll
    for (int mi = 0; mi < 4; ++mi)
        #pragma unroll
        for (int ni = 0; ni < 4; ++ni)
            acc2[mi][ni] = (floatx4){0.f, 0.f, 0.f, 0.f};

    #pragma unroll
    for (int kc = 0; kc < 8; ++kc) {
        short8 afr[4], bfr[4];
        #pragma unroll
        for (int mi = 0; mi < 4; ++mi)
            afr[mi] = *(const short8*)&hfr[((kc * 4 + mi) * 64 + (l ^ kc)) * 8];
        #pragma unroll
        for (int ni = 0; ni < 4; ++ni)
            bfr[ni] = *(const short8*)(B2f + ((((size_t)w * 8 + kc) * 4 + ni) * 64 + l) * 8);
        #pragma unroll
        for (int mi = 0; mi < 4; ++mi)
            #pragma unroll
            for (int ni = 0; ni < 4; ++ni)
                acc2[mi][ni] = __builtin_amdgcn_mfma_f32_16x16x32_bf16(afr[mi], bfr[ni], acc2[mi][ni], 0, 0, 0);
    }

    #pragma unroll
    for (int mi = 0; mi < 4; ++mi)
        #pragma unroll
        for (int ni = 0; ni < 4; ++ni) {
            int col = w * 64 + ni * 16 + (l & 15);
            #pragma unroll
            for (int j = 0; j < 4; ++j) {
                int r = b0 + mi * 16 + (l >> 4) * 4 + j;
                float v = acc2[mi][ni][j];
                if (col < 128) {
                    out[(size_t)r * 128 + col] = v + Ub[col];
                } else {
                    float xx = v + Wb[col - 128];
                    float sp = fmaxf(xx, 0.f) + log1pf(expf(-fabsf(xx)));
                    out[(size_t)Bsz * 128 + (size_t)r * 128 + (col - 128)] = sp;
                }
            }
        }
}

// ==================== launch ====================
extern "C" void kernel_launch(void* const* d_in, const int* in_sizes, int n_in,
                              void* d_out, int out_size, void* d_ws, size_t ws_size,
                              hipStream_t stream)
{
    const int*   tgt = (const int*)d_in[0];
    const int*   ctx = (const int*)d_in[1];
    const float* R   = (const float*)d_in[2];
    const float* Mw  = (const float*)d_in[3];
    const float* Mb  = (const float*)d_in[4];
    const float* Uw  = (const float*)d_in[5];
    const float* Ub  = (const float*)d_in[6];
    const float* Ww  = (const float*)d_in[7];
    const float* Wb  = (const float*)d_in[8];
    float* out = (float*)d_out;
    const int Bsz = in_sizes[0];
    const int Vn  = in_sizes[2] / D_EMB;

    char* ws = (char*)d_ws;
    size_t offG   = 0;                               // V*256 bf16 = 51.2 MB
    size_t offT   = offG + (size_t)Vn * 512;         // B*256 f32  = 16.8 MB
    size_t offM1f = offT + (size_t)Bsz * 1024;
    size_t offM2f = offM1f + 65536;
    size_t offB2f = offM2f + 65536;

    short* G   = (short*)(ws + offG);
    float* Tt  = (float*)(ws + offT);
    short* M1f = (short*)(ws + offM1f);
    short* M2f = (short*)(ws + offM2f);
    short* B2f = (short*)(ws + offB2f);

    prep_main<<<64, 256, 0, stream>>>(Mw, Uw, Ww, M1f, M2f, B2f);
    k_t<<<Bsz / 64, 256, 0, stream>>>(tgt, R, M2f, Mb, Tt);
    k_g<<<(Vn + 63) / 64, 256, 0, stream>>>(R, M1f, G, Vn);
    k_hh<<<Bsz / 64, 256, 0, stream>>>(ctx, G, Tt, B2f, Ub, Wb, out, Bsz);
}

// Round 5
// 64.998 us; speedup vs baseline: 5.4949x; 1.3291x over previous
//
#include <hip/hip_runtime.h>
#include <hip/hip_bf16.h>

typedef __attribute__((ext_vector_type(8))) short short8;
typedef __attribute__((ext_vector_type(4))) float floatx4;

static __device__ __forceinline__ short f2bf(float f) {
    union { float f; unsigned u; } v; v.f = f;
    unsigned r = v.u + 0x7fffu + ((v.u >> 16) & 1u);
    return (short)(r >> 16);
}
static __device__ __forceinline__ float bf2f(short s) {
    union { unsigned u; float f; } v; v.u = ((unsigned)(unsigned short)s) << 16;
    return v.f;
}

#define C_CTX 10
#define D_EMB 128
#define E_DIM 256

// ---- prep: bf16 MFMA B-fragments for M1 (cols 0:128 of Mw), M2 (cols 128:256), U|W ----
__global__ void prep_main(const float* __restrict__ Mw, const float* __restrict__ Uw,
                          const float* __restrict__ Ww, short* __restrict__ M1f,
                          short* __restrict__ M2f, short* __restrict__ B2f)
{
    int u = blockIdx.x * 256 + threadIdx.x;   // 0..16383
    const float* src;
    short* dst;
    if (u < 8192) {
        int f = u & 4095;
        int l = f & 63, kc = (f >> 6) & 3, grp = f >> 8;     // grp 0..15
        int e = grp * 16 + (l & 15);
        int k = kc * 32 + (l >> 4) * 8 + ((u < 4096) ? 0 : 128);
        src = Mw + (size_t)e * E_DIM + k;
        dst = ((u < 4096) ? M1f : M2f) + (size_t)f * 8;
    } else {
        int f = u - 8192;
        int l = f & 63, ni = (f >> 6) & 3, kc = (f >> 8) & 7, w = f >> 11;
        int e = w * 64 + ni * 16 + (l & 15);
        int k = kc * 32 + (l >> 4) * 8;
        src = (e < 128) ? (Uw + (size_t)e * E_DIM + k)
                        : (Ww + (size_t)(e - 128) * E_DIM + k);
        dst = B2f + (size_t)f * 8;
    }
    float4 x = *(const float4*)src;
    float4 y = *(const float4*)(src + 4);
    short8 o;
    o[0]=f2bf(x.x); o[1]=f2bf(x.y); o[2]=f2bf(x.z); o[3]=f2bf(x.w);
    o[4]=f2bf(y.x); o[5]=f2bf(y.y); o[6]=f2bf(y.z); o[7]=f2bf(y.w);
    *(short8*)dst = o;
}

// ---- k_gt2: blocks [0, NG): G = R @ M1^T (bf16). blocks [NG, NG+NT): Tt = R[tgt]@M2^T + Mb (f32)
__global__ __launch_bounds__(256, 4)
void k_gt2(const float* __restrict__ R, const short* __restrict__ M1f,
           const short* __restrict__ M2f, const float* __restrict__ Mb,
           const int* __restrict__ tgt, short* __restrict__ G,
           float* __restrict__ Tt, int V, int NG)
{
    __shared__ __align__(16) short buf[64 * 264];   // 33 KB; first 16 KB doubles as A-frag stage
    __shared__ int tids[64];
    const int t = threadIdx.x, w = t >> 6, l = t & 63;
    const bool isG = (int)blockIdx.x < NG;
    const int r0 = (isG ? blockIdx.x : (blockIdx.x - NG)) * 64;

    if (!isG && t < 64) tids[t] = tgt[r0 + t];
    if (!isG) __syncthreads();

    // stage A fragments (frag-linear, conflict-free): 1024 short8 units
    #pragma unroll
    for (int i = 0; i < 4; ++i) {
        int fa = t + i * 256;
        int li = fa & 63, frag = fa >> 6;     // 0..15
        int kc = frag >> 2, mi = frag & 3;
        int r = mi * 16 + (li & 15);
        int k = kc * 32 + (li >> 4) * 8;
        int gr;
        if (isG) { gr = r0 + r; if (gr >= V) gr = V - 1; }
        else     { gr = tids[r]; }
        const float* s = R + (size_t)gr * D_EMB + k;
        float4 x = *(const float4*)s;
        float4 y = *(const float4*)(s + 4);
        short8 v;
        v[0]=f2bf(x.x); v[1]=f2bf(x.y); v[2]=f2bf(x.z); v[3]=f2bf(x.w);
        v[4]=f2bf(y.x); v[5]=f2bf(y.y); v[6]=f2bf(y.z); v[7]=f2bf(y.w);
        *(short8*)&buf[fa * 8] = v;
    }
    __syncthreads();

    const short* Bf = isG ? M1f : M2f;
    floatx4 acc[4][4];
    #pragma unroll
    for (int mi = 0; mi < 4; ++mi)
        #pragma unroll
        for (int ni = 0; ni < 4; ++ni)
            acc[mi][ni] = (floatx4){0.f, 0.f, 0.f, 0.f};

    #pragma unroll
    for (int kc = 0; kc < 4; ++kc) {
        short8 afr[4], bfr[4];
        #pragma unroll
        for (int mi = 0; mi < 4; ++mi)
            afr[mi] = *(const short8*)&buf[((kc * 4 + mi) * 64 + l) * 8];
        #pragma unroll
        for (int ni = 0; ni < 4; ++ni)
            bfr[ni] = *(const short8*)(Bf + (((size_t)(w * 4 + ni) * 4 + kc) * 64 + l) * 8);
        #pragma unroll
        for (int mi = 0; mi < 4; ++mi)
            #pragma unroll
            for (int ni = 0; ni < 4; ++ni)
                acc[mi][ni] = __builtin_amdgcn_mfma_f32_16x16x32_bf16(afr[mi], bfr[ni], acc[mi][ni], 0, 0, 0);
    }

    if (isG) {
        __syncthreads();   // A-frag region dead
        // transpose acc -> row-major [64][264]
        #pragma unroll
        for (int mi = 0; mi < 4; ++mi)
            #pragma unroll
            for (int ni = 0; ni < 4; ++ni) {
                int col = w * 64 + ni * 16 + (l & 15);
                #pragma unroll
                for (int j = 0; j < 4; ++j) {
                    int row = mi * 16 + (l >> 4) * 4 + j;
                    buf[row * 264 + col] = f2bf(acc[mi][ni][j]);
                }
            }
        __syncthreads();
        // coalesced stores: 2048 short8 units
        #pragma unroll
        for (int i = 0; i < 8; ++i) {
            int u = t + i * 256;
            int row = u >> 5, c8 = (u & 31) * 8;
            int gr = r0 + row;
            if (gr < V)
                *(short8*)(G + (size_t)gr * 256 + c8) = *(const short8*)&buf[row * 264 + c8];
        }
    } else {
        #pragma unroll
        for (int mi = 0; mi < 4; ++mi)
            #pragma unroll
            for (int ni = 0; ni < 4; ++ni) {
                int col = w * 64 + ni * 16 + (l & 15);
                float mb = Mb[col];
                #pragma unroll
                for (int j = 0; j < 4; ++j) {
                    int row = mi * 16 + (l >> 4) * 4 + j;
                    Tt[(size_t)(r0 + row) * E_DIM + col] = acc[mi][ni][j] + mb;
                }
            }
    }
}

// ---- k_hh: 16 b's/block. h = sum_c relu(G[ctx] + Tt) -> LDS frags -> heads GEMM -> out
// frag element (row=bl 0..15, k = kc*32 + sub*8 + 0..7) stored at
// hfr[(kc*64 + ((sub*16+bl) ^ kc)) * 8]; GEMM reads lane l at hfr[(kc*64 + (l^kc))*8].
__global__ __launch_bounds__(256, 4)
void k_hh(const int* __restrict__ ctx, const short* __restrict__ G,
          const float* __restrict__ Tt, const short* __restrict__ B2f,
          const float* __restrict__ Ub, const float* __restrict__ Wb,
          float* __restrict__ out, int Bsz)
{
    __shared__ __align__(16) short hfr[8 * 64 * 8];   // 8 KB
    __shared__ int ids[16 * C_CTX];
    const int t = threadIdx.x, w = t >> 6, l = t & 63;
    const int b0 = blockIdx.x * 16;

    if (t < 16 * C_CTX) ids[t] = ctx[(size_t)b0 * C_CTX + t];
    __syncthreads();

    const int hw = l >> 5;               // half-wave
    const int i5 = l & 31;
    const int kcc = i5 & 7, sub = i5 >> 3;
    const int c8 = kcc * 32 + sub * 8;   // col base (permutation covers all 32 chunks)

    #pragma unroll
    for (int p = 0; p < 2; ++p) {
        int bl = p * 8 + w * 2 + hw;     // local row 0..15
        const float* tp = Tt + (size_t)(b0 + bl) * E_DIM + c8;
        float4 x = *(const float4*)tp;
        float4 y = *(const float4*)(tp + 4);
        float tv[8] = {x.x, x.y, x.z, x.w, y.x, y.y, y.z, y.w};
        float acc[8] = {0.f, 0.f, 0.f, 0.f, 0.f, 0.f, 0.f, 0.f};
        #pragma unroll
        for (int c = 0; c < C_CTX; ++c) {
            short8 g = *(const short8*)(G + (size_t)ids[bl * C_CTX + c] * E_DIM + c8);
            #pragma unroll
            for (int j = 0; j < 8; ++j)
                acc[j] += fmaxf(bf2f(g[j]) + tv[j], 0.f);
        }
        int sp = (sub * 16 + bl) ^ kcc;
        short8 o;
        #pragma unroll
        for (int j = 0; j < 8; ++j) o[j] = f2bf(acc[j]);
        *(short8*)&hfr[(kcc * 64 + sp) * 8] = o;
    }
    __syncthreads();

    // heads GEMM: 16 rows x 256 cols x K=256
    floatx4 acc2[4];
    #pragma unroll
    for (int ni = 0; ni < 4; ++ni)
        acc2[ni] = (floatx4){0.f, 0.f, 0.f, 0.f};

    #pragma unroll
    for (int kc = 0; kc < 8; ++kc) {
        short8 afr = *(const short8*)&hfr[(kc * 64 + (l ^ kc)) * 8];
        short8 bfr[4];
        #pragma unroll
        for (int ni = 0; ni < 4; ++ni)
            bfr[ni] = *(const short8*)(B2f + ((((size_t)w * 8 + kc) * 4 + ni) * 64 + l) * 8);
        #pragma unroll
        for (int ni = 0; ni < 4; ++ni)
            acc2[ni] = __builtin_amdgcn_mfma_f32_16x16x32_bf16(afr, bfr[ni], acc2[ni], 0, 0, 0);
    }

    #pragma unroll
    for (int ni = 0; ni < 4; ++ni) {
        int col = w * 64 + ni * 16 + (l & 15);
        #pragma unroll
        for (int j = 0; j < 4; ++j) {
            int r = b0 + (l >> 4) * 4 + j;
            float v = acc2[ni][j];
            if (col < 128) {
                out[(size_t)r * 128 + col] = v + Ub[col];
            } else {
                float xx = v + Wb[col - 128];
                float sp = fmaxf(xx, 0.f) + log1pf(expf(-fabsf(xx)));
                out[(size_t)Bsz * 128 + (size_t)r * 128 + (col - 128)] = sp;
            }
        }
    }
}

// ==================== launch ====================
extern "C" void kernel_launch(void* const* d_in, const int* in_sizes, int n_in,
                              void* d_out, int out_size, void* d_ws, size_t ws_size,
                              hipStream_t stream)
{
    const int*   tgt = (const int*)d_in[0];
    const int*   ctx = (const int*)d_in[1];
    const float* R   = (const float*)d_in[2];
    const float* Mw  = (const float*)d_in[3];
    const float* Mb  = (const float*)d_in[4];
    const float* Uw  = (const float*)d_in[5];
    const float* Ub  = (const float*)d_in[6];
    const float* Ww  = (const float*)d_in[7];
    const float* Wb  = (const float*)d_in[8];
    float* out = (float*)d_out;
    const int Bsz = in_sizes[0];
    const int Vn  = in_sizes[2] / D_EMB;

    char* ws = (char*)d_ws;
    size_t offG   = 0;                               // V*256 bf16 = 51.2 MB
    size_t offT   = offG + (size_t)Vn * 512;         // B*256 f32  = 16.8 MB
    size_t offM1f = offT + (size_t)Bsz * 1024;
    size_t offM2f = offM1f + 65536;
    size_t offB2f = offM2f + 65536;

    short* G   = (short*)(ws + offG);
    float* Tt  = (float*)(ws + offT);
    short* M1f = (short*)(ws + offM1f);
    short* M2f = (short*)(ws + offM2f);
    short* B2f = (short*)(ws + offB2f);

    const int NG = (Vn + 63) / 64;
    const int NT = Bsz / 64;

    prep_main<<<64, 256, 0, stream>>>(Mw, Uw, Ww, M1f, M2f, B2f);
    k_gt2<<<NG + NT, 256, 0, stream>>>(R, M1f, M2f, Mb, tgt, G, Tt, Vn, NG);
    k_hh<<<Bsz / 16, 256, 0, stream>>>(ctx, G, Tt, B2f, Ub, Wb, out, Bsz);
}